// Round 1
// baseline (136.752 us; speedup 1.0000x reference)
//
#include <hip/hip_runtime.h>
#include <math.h>

#define TPB 512

// One block per sample. Input image staged to LDS (padded for SAME edges),
// conv weights held in registers (4 channels/thread), all three heads fused.
__global__ __launch_bounds__(TPB, 2)
void pattern_branch_kernel(const float* __restrict__ in,      // [B,64,64,3]
                           const float* __restrict__ conv_w,  // [3,3,3,128] = [27,128]
                           const float* __restrict__ conv_b,  // [128]
                           const float* __restrict__ match_w, // [128]
                           const float* __restrict__ match_b, // [1]
                           const float* __restrict__ pat_w,   // [32768]
                           const float* __restrict__ pat_b,   // [1]
                           const float* __restrict__ base_w,  // [131072,3]
                           const float* __restrict__ base_b,  // [3]
                           const int*   __restrict__ psi,     // [32]
                           float* __restrict__ out)           // [B,3]
{
    constexpr int ROWF4 = 50;            // float4 per padded row (200 floats)
    constexpr int ROWF  = 200;
    __shared__ float4 xlds4[65 * ROWF4]; // 52 KB: rows 0..64, cols padded
    __shared__ float  red[8][5];

    const float* xlds = (const float*)xlds4;
    const int b   = blockIdx.x;
    const int tid = threadIdx.x;

    // ---- stage input: zero (covers SAME padding: row 64, col 64), then fill
    for (int s = tid; s < 65 * ROWF4; s += TPB) xlds4[s] = make_float4(0.f, 0.f, 0.f, 0.f);
    __syncthreads();
    const float4* inp4 = (const float4*)(in + (size_t)b * 12288);
    for (int s = tid; s < 64 * 48; s += TPB) {      // 64 rows x 48 float4 (192 floats)
        int r = s / 48;
        int q = s - r * 48;
        xlds4[r * ROWF4 + q] = inp4[s];
    }
    __syncthreads();

    // ---- per-thread conv weights: channels c = (tid&31) + 32j
    const int lane31 = tid & 31;
    const int grp    = tid >> 5;     // 0..15
    float w[4][27], bias[4], mw[4];
    #pragma unroll
    for (int j = 0; j < 4; ++j) {
        int c = lane31 + 32 * j;
        bias[j] = conv_b[c];
        mw[j]   = match_w[c];
        #pragma unroll
        for (int k = 0; k < 27; ++k) w[j][k] = conv_w[k * 128 + c];
    }

    float s_match = 0.f, sb0 = 0.f, sb1 = 0.f, sb2 = 0.f;

    // ---- main loop: each iter = 4 ow x 4 c features, shared LDS row reads
    for (int it = 0; it < 16; ++it) {
        int slot = it * 16 + grp;    // 0..255 = (oh:32) x (q:8)
        int oh = slot >> 3;
        int q  = slot & 7;           // ow = 4q+v
        float acc[4][4];
        #pragma unroll
        for (int v = 0; v < 4; ++v)
            #pragma unroll
            for (int j = 0; j < 4; ++j) acc[v][j] = bias[j];

        #pragma unroll
        for (int kh = 0; kh < 3; ++kh) {
            // cols 8q..8q+8 (9 px = 27 floats) -> 7 aligned float4 from f4 idx 6q
            float xr[28];
            const float4* rp = &xlds4[(2 * oh + kh) * ROWF4 + 6 * q];
            #pragma unroll
            for (int u = 0; u < 7; ++u) {
                float4 v4 = rp[u];
                xr[4*u] = v4.x; xr[4*u+1] = v4.y; xr[4*u+2] = v4.z; xr[4*u+3] = v4.w;
            }
            #pragma unroll
            for (int v = 0; v < 4; ++v)
                #pragma unroll
                for (int t9 = 0; t9 < 9; ++t9) {   // t9 = kw*3+ci
                    float xv = xr[6 * v + t9];
                    int k = kh * 9 + t9;
                    acc[v][0] = fmaf(xv, w[0][k], acc[v][0]);
                    acc[v][1] = fmaf(xv, w[1][k], acc[v][1]);
                    acc[v][2] = fmaf(xv, w[2][k], acc[v][2]);
                    acc[v][3] = fmaf(xv, w[3][k], acc[v][3]);
                }
        }
        #pragma unroll
        for (int v = 0; v < 4; ++v) {
            int hw = oh * 32 + 4 * q + v;
            const float* bp = base_w + (size_t)(hw * 128 + lane31) * 3;
            #pragma unroll
            for (int j = 0; j < 4; ++j) {
                float fv = fmaxf(acc[v][j], 0.f);
                s_match = fmaf(mw[j], fv, s_match);
                const float* bpj = bp + j * 96;    // 32 channels * 3
                sb0 = fmaf(fv, bpj[0], sb0);
                sb1 = fmaf(fv, bpj[1], sb1);
                sb2 = fmaf(fv, bpj[2], sb2);
            }
        }
    }

    // ---- pattern phase: recompute conv on gathered channels psi[k]
    float s_pat = 0.f;
    {
        const int lane8 = tid & 7;
        const int pgrp  = tid >> 3;  // 0..63
        int pk[4];
        float pbias[4];
        float pw[4][27];             // reuses the w[] registers (w is dead)
        #pragma unroll
        for (int j = 0; j < 4; ++j) {
            int k = lane8 + 8 * j;
            pk[j] = k;
            int c = psi[k];
            pbias[j] = conv_b[c];
            #pragma unroll
            for (int kk = 0; kk < 27; ++kk) pw[j][kk] = conv_w[kk * 128 + c];
        }
        for (int it = 0; it < 16; ++it) {
            int hw = it * 64 + pgrp;
            int oh = hw >> 5, ow = hw & 31;
            float a0 = pbias[0], a1 = pbias[1], a2 = pbias[2], a3 = pbias[3];
            #pragma unroll
            for (int kh = 0; kh < 3; ++kh) {
                float xr[10];        // 9 floats from float offset 6*ow (8B aligned)
                const float2* rp = (const float2*)(xlds + (2 * oh + kh) * ROWF) + 3 * ow;
                #pragma unroll
                for (int u = 0; u < 5; ++u) { float2 v2 = rp[u]; xr[2*u] = v2.x; xr[2*u+1] = v2.y; }
                #pragma unroll
                for (int t9 = 0; t9 < 9; ++t9) {
                    float xv = xr[t9];
                    int k = kh * 9 + t9;
                    a0 = fmaf(xv, pw[0][k], a0);
                    a1 = fmaf(xv, pw[1][k], a1);
                    a2 = fmaf(xv, pw[2][k], a2);
                    a3 = fmaf(xv, pw[3][k], a3);
                }
            }
            const float* pwp = pat_w + hw * 32;
            s_pat = fmaf(fmaxf(a0, 0.f), pwp[pk[0]], s_pat);
            s_pat = fmaf(fmaxf(a1, 0.f), pwp[pk[1]], s_pat);
            s_pat = fmaf(fmaxf(a2, 0.f), pwp[pk[2]], s_pat);
            s_pat = fmaf(fmaxf(a3, 0.f), pwp[pk[3]], s_pat);
        }
    }

    // ---- reduction: wave shuffle then LDS
    float vals[5] = { s_match, sb0, sb1, sb2, s_pat };
    #pragma unroll
    for (int off = 32; off > 0; off >>= 1)
        #pragma unroll
        for (int v = 0; v < 5; ++v)
            vals[v] += __shfl_down(vals[v], off, 64);
    int wv = tid >> 6, lane = tid & 63;
    if (lane == 0) {
        #pragma unroll
        for (int v = 0; v < 5; ++v) red[wv][v] = vals[v];
    }
    __syncthreads();
    if (tid == 0) {
        float t[5] = {0.f, 0.f, 0.f, 0.f, 0.f};
        for (int wj = 0; wj < 8; ++wj)
            #pragma unroll
            for (int v = 0; v < 5; ++v) t[v] += red[wj][v];
        float score = t[0] * (1.f / 1024.f) + match_b[0];
        float p = 1.f / (1.f + expf(-(t[4] + pat_b[0])));
        float l0 = t[1] + base_b[0], l1 = t[2] + base_b[1], l2 = t[3] + base_b[2];
        float m = fmaxf(l0, fmaxf(l1, l2));
        float e0 = expf(l0 - m), e1 = expf(l1 - m), e2 = expf(l2 - m);
        float inv = 1.f / (e0 + e1 + e2);
        bool use_pat = (score > 0.f) && (p >= 0.5f);
        float o0, o1, o2;
        if (use_pat) { o0 = p; o1 = 0.5f * (1.f - p); o2 = o1; }
        else         { o0 = e0 * inv; o1 = e1 * inv; o2 = e2 * inv; }
        out[b * 3 + 0] = o0;
        out[b * 3 + 1] = o1;
        out[b * 3 + 2] = o2;
    }
}

extern "C" void kernel_launch(void* const* d_in, const int* in_sizes, int n_in,
                              void* d_out, int out_size, void* d_ws, size_t ws_size,
                              hipStream_t stream) {
    const float* in      = (const float*)d_in[0];
    const float* conv_w  = (const float*)d_in[1];
    const float* conv_b  = (const float*)d_in[2];
    const float* match_w = (const float*)d_in[3];
    const float* match_b = (const float*)d_in[4];
    const float* pat_w   = (const float*)d_in[5];
    const float* pat_b   = (const float*)d_in[6];
    const float* base_w  = (const float*)d_in[7];
    const float* base_b  = (const float*)d_in[8];
    const int*   psi     = (const int*)d_in[9];
    float* out = (float*)d_out;

    int B = in_sizes[0] / (64 * 64 * 3);   // 256
    pattern_branch_kernel<<<B, TPB, 0, stream>>>(
        in, conv_w, conv_b, match_w, match_b, pat_w, pat_b,
        base_w, base_b, psi, out);
}

// Round 2
// 116.190 us; speedup vs baseline: 1.1770x; 1.1770x over previous
//
#include <hip/hip_runtime.h>
#include <math.h>

#define TPB 1024

// ---------------------------------------------------------------------------
// Prep kernel: build fused weight table wq[hw*128+c] = {bw0, bw1, bw2, patc}
// where patc = sum_{k: psi[k]==c} pat_w[hw*32+k]. Removes the entire
// pattern-recompute phase from the main kernel (pat head is linear in feats).
// ---------------------------------------------------------------------------
__global__ __launch_bounds__(256)
void prep_weights(const float* __restrict__ base_w,  // [131072,3]
                  const float* __restrict__ pat_w,   // [32768]
                  const int*   __restrict__ psi,     // [32]
                  float4* __restrict__ wq)           // [131072]
{
    int idx = blockIdx.x * 256 + threadIdx.x;        // 0..131071
    int hw = idx >> 7, c = idx & 127;
    const float* bp = base_w + (size_t)idx * 3;
    float b0 = bp[0], b1 = bp[1], b2 = bp[2];
    float pc = 0.f;
    const float* pr = pat_w + hw * 32;
    #pragma unroll
    for (int k = 0; k < 32; ++k)
        pc += (psi[k] == c) ? pr[k] : 0.f;
    wq[idx] = make_float4(b0, b1, b2, pc);
}

// ---------------------------------------------------------------------------
// Main kernel: one block per sample, 1024 threads = 16 waves (4/SIMD).
// Thread owns 2 channels: c = (tid&31) + 32*((tid>>5)&1) + 64*jj, jj in {0,1}.
// Spatial group sg = tid>>6 in [0,16) covers (oh,q) slots over 16 iters.
// Conv weights in registers (w[2][27]); input image in LDS (padded SAME).
// ---------------------------------------------------------------------------
__global__ __launch_bounds__(TPB, 4)
void pattern_branch_kernel(const float* __restrict__ in,      // [B,64,64,3]
                           const float* __restrict__ conv_w,  // [27,128]
                           const float* __restrict__ conv_b,  // [128]
                           const float* __restrict__ match_w, // [128]
                           const float* __restrict__ match_b, // [1]
                           const float* __restrict__ pat_b,   // [1]
                           const float* __restrict__ base_b,  // [3]
                           const float4* __restrict__ wq,     // [131072] fused
                           float* __restrict__ out)           // [B,3]
{
    constexpr int ROWF4 = 50;            // float4 per padded row (200 floats)
    __shared__ float4 xlds4[65 * ROWF4]; // 52 KB
    __shared__ float  red[16][5];

    const int b   = blockIdx.x;
    const int tid = threadIdx.x;

    // ---- stage input: zero (covers SAME padding row 64 / col 64), then fill
    for (int s = tid; s < 65 * ROWF4; s += TPB) xlds4[s] = make_float4(0.f, 0.f, 0.f, 0.f);
    __syncthreads();
    const float4* inp4 = (const float4*)(in + (size_t)b * 12288);
    for (int s = tid; s < 64 * 48; s += TPB) {      // 64 rows x 48 float4
        int r = s / 48;
        int q = s - r * 48;
        xlds4[r * ROWF4 + q] = inp4[s];
    }
    __syncthreads();

    // ---- per-thread conv weights: 2 channels, 64 apart
    const int lane31 = tid & 31;
    const int cg     = (tid >> 5) & 1;
    const int sg     = tid >> 6;         // 0..15
    const int c0     = lane31 + 32 * cg;
    float w[2][27], bias[2], mw[2];
    #pragma unroll
    for (int jj = 0; jj < 2; ++jj) {
        int c = c0 + 64 * jj;
        bias[jj] = conv_b[c];
        mw[jj]   = match_w[c];
        #pragma unroll
        for (int k = 0; k < 27; ++k) w[jj][k] = conv_w[k * 128 + c];
    }

    float s_match = 0.f, sb0 = 0.f, sb1 = 0.f, sb2 = 0.f, s_pat = 0.f;

    // ---- main loop: per iter = 4 ow x 2 ch, full-wave-broadcast LDS reads
    for (int it = 0; it < 16; ++it) {
        int slot = it * 16 + sg;         // 0..255 = (oh:32) x (q:8)
        int oh = slot >> 3;
        int q  = slot & 7;               // ow = 4q+v
        float acc[4][2];
        #pragma unroll
        for (int v = 0; v < 4; ++v) { acc[v][0] = bias[0]; acc[v][1] = bias[1]; }

        #pragma unroll
        for (int kh = 0; kh < 3; ++kh) {
            // px cols 8q..8q+8 -> floats 24q..24q+27 -> 7 aligned float4
            float xr[28];
            const float4* rp = &xlds4[(2 * oh + kh) * ROWF4 + 6 * q];
            #pragma unroll
            for (int u = 0; u < 7; ++u) {
                float4 v4 = rp[u];
                xr[4*u] = v4.x; xr[4*u+1] = v4.y; xr[4*u+2] = v4.z; xr[4*u+3] = v4.w;
            }
            #pragma unroll
            for (int v = 0; v < 4; ++v)
                #pragma unroll
                for (int t9 = 0; t9 < 9; ++t9) {   // t9 = kw*3+ci
                    float xv = xr[6 * v + t9];
                    int k = kh * 9 + t9;
                    acc[v][0] = fmaf(xv, w[0][k], acc[v][0]);
                    acc[v][1] = fmaf(xv, w[1][k], acc[v][1]);
                }
        }
        // epilogue: fused weight table, coalesced float4 per (v,jj)
        #pragma unroll
        for (int v = 0; v < 4; ++v) {
            int hw = oh * 32 + 4 * q + v;
            const float4* wqp = wq + hw * 128 + c0;
            #pragma unroll
            for (int jj = 0; jj < 2; ++jj) {
                float fv = fmaxf(acc[v][jj], 0.f);
                float4 wv = wqp[64 * jj];
                s_match = fmaf(mw[jj], fv, s_match);
                sb0   = fmaf(fv, wv.x, sb0);
                sb1   = fmaf(fv, wv.y, sb1);
                sb2   = fmaf(fv, wv.z, sb2);
                s_pat = fmaf(fv, wv.w, s_pat);
            }
        }
    }

    // ---- reduction: wave shuffle then LDS across 16 waves
    float vals[5] = { s_match, sb0, sb1, sb2, s_pat };
    #pragma unroll
    for (int off = 32; off > 0; off >>= 1)
        #pragma unroll
        for (int v = 0; v < 5; ++v)
            vals[v] += __shfl_down(vals[v], off, 64);
    int wv = tid >> 6, lane = tid & 63;
    if (lane == 0) {
        #pragma unroll
        for (int v = 0; v < 5; ++v) red[wv][v] = vals[v];
    }
    __syncthreads();
    if (tid == 0) {
        float t[5] = {0.f, 0.f, 0.f, 0.f, 0.f};
        for (int wj = 0; wj < 16; ++wj)
            #pragma unroll
            for (int v = 0; v < 5; ++v) t[v] += red[wj][v];
        float score = t[0] * (1.f / 1024.f) + match_b[0];
        float p = 1.f / (1.f + expf(-(t[4] + pat_b[0])));
        float l0 = t[1] + base_b[0], l1 = t[2] + base_b[1], l2 = t[3] + base_b[2];
        float m = fmaxf(l0, fmaxf(l1, l2));
        float e0 = expf(l0 - m), e1 = expf(l1 - m), e2 = expf(l2 - m);
        float inv = 1.f / (e0 + e1 + e2);
        bool use_pat = (score > 0.f) && (p >= 0.5f);
        float o0, o1, o2;
        if (use_pat) { o0 = p; o1 = 0.5f * (1.f - p); o2 = o1; }
        else         { o0 = e0 * inv; o1 = e1 * inv; o2 = e2 * inv; }
        out[b * 3 + 0] = o0;
        out[b * 3 + 1] = o1;
        out[b * 3 + 2] = o2;
    }
}

extern "C" void kernel_launch(void* const* d_in, const int* in_sizes, int n_in,
                              void* d_out, int out_size, void* d_ws, size_t ws_size,
                              hipStream_t stream) {
    const float* in      = (const float*)d_in[0];
    const float* conv_w  = (const float*)d_in[1];
    const float* conv_b  = (const float*)d_in[2];
    const float* match_w = (const float*)d_in[3];
    const float* match_b = (const float*)d_in[4];
    const float* pat_w   = (const float*)d_in[5];
    const float* pat_b   = (const float*)d_in[6];
    const float* base_w  = (const float*)d_in[7];
    const float* base_b  = (const float*)d_in[8];
    const int*   psi     = (const int*)d_in[9];
    float* out = (float*)d_out;

    float4* wq = (float4*)d_ws;   // 131072 * 16 B = 2 MB scratch

    prep_weights<<<512, 256, 0, stream>>>(base_w, pat_w, psi, wq);

    int B = in_sizes[0] / (64 * 64 * 3);   // 256
    pattern_branch_kernel<<<B, TPB, 0, stream>>>(
        in, conv_w, conv_b, match_w, match_b, pat_b, base_b, wq, out);
}